// Round 1
// baseline (658.730 us; speedup 1.0000x reference)
//
#include <hip/hip_runtime.h>

// VectorQuantizer fused kernel — round 1: fp32 vector-ALU baseline.
//
// score[k] = ||e_k||^2 - 2 * dot(x_p, e_k)   (x^2 term dropped: constant in k)
// argmin over k must match jnp.argmin (first minimal index) — strict-< updates
// in ascending k order + explicit tie-break in the cross-thread reduce.
//
// Pipeline (all on `stream`):
//   k_zero  : zero the loss accumulator in ws (ws is poisoned 0xAA each call)
//   k_e2    : e2[k] = ||e_k||^2
//   k_et    : transpose embeddings -> ET[c][k] (coalesced GEMM staging)
//   k_main  : fused GEMM + argmin + gather + transposed store + loss partials
//   k_final : loss = 2 * S / N  into d_out[16777216]

#define C_DIM   256
#define K_CODES 1024
#define HW      4096
#define BATCH   16
#define N_OUT   (BATCH * C_DIM * HW)   // 16777216 z_q elements; loss at [N_OUT]
#define TPX     64                     // pixels per block
#define TKC     64                     // codes per k-chunk
#define CSEG    64                     // c-segment staged per round

__global__ void k_zero(float* ws) { ws[0] = 0.f; }

__global__ __launch_bounds__(256) void k_e2(const float* __restrict__ emb,
                                            float* __restrict__ e2) {
  int k = blockIdx.x * 256 + threadIdx.x;
  const float* e = emb + (size_t)k * C_DIM;
  float s = 0.f;
#pragma unroll 8
  for (int c = 0; c < C_DIM; ++c) s += e[c] * e[c];
  e2[k] = s;
}

__global__ __launch_bounds__(256) void k_et(const float* __restrict__ emb,
                                            float* __restrict__ et) {
  int i = blockIdx.x * 256 + threadIdx.x;   // grid = 1024 -> 262144 elements
  int k = i >> 8;
  int c = i & 255;
  et[(size_t)c * K_CODES + k] = emb[i];
}

__global__ __launch_bounds__(256, 4) void k_main(
    const float* __restrict__ x, const float* __restrict__ emb,
    const float* __restrict__ esrc, int et_flag,
    const float* __restrict__ e2, float* __restrict__ out,
    float* __restrict__ loss_acc) {
  // 32 KiB staging buffer; reused for the argmin reduce after the k-loop.
  __shared__ float smem[CSEG * TPX + CSEG * TKC];  // 8192 floats
  float* xs = smem;                 // [cs][p]  16 KiB
  float* es = smem + CSEG * TPX;    // [cs][kk] 16 KiB
  // post-compute aliases (guarded by __syncthreads):
  float* red_d  = smem;                          // [64 pixels][16 kg]
  int*   red_i  = (int*)(smem + TPX * 16);       // [64][16]
  int*   bidx_s = (int*)(smem + TPX * 32);       // [64]
  float* lred   = smem + TPX * 32 + TPX;         // [4]

  const int t    = threadIdx.x;
  const int tile = blockIdx.x;          // 1024 tiles = 16 batches * 64
  const int b    = tile >> 6;
  const int p0   = (tile & 63) << 6;    // pixel offset within batch image
  const float* xb = x + (size_t)b * C_DIM * HW + p0;

  const int pg = t & 15;   // pixel group: pixels pg*4 .. pg*4+3
  const int kg = t >> 4;   // code group within chunk: codes kg*4 .. kg*4+3

  float best0 = 1e30f, best1 = 1e30f, best2 = 1e30f, best3 = 1e30f;
  int   bi0 = 0, bi1 = 0, bi2 = 0, bi3 = 0;

  for (int kc = 0; kc < K_CODES / TKC; ++kc) {
    const int k0 = kc * TKC;
    float acc00 = 0.f, acc01 = 0.f, acc02 = 0.f, acc03 = 0.f;
    float acc10 = 0.f, acc11 = 0.f, acc12 = 0.f, acc13 = 0.f;
    float acc20 = 0.f, acc21 = 0.f, acc22 = 0.f, acc23 = 0.f;
    float acc30 = 0.f, acc31 = 0.f, acc32 = 0.f, acc33 = 0.f;

    for (int cseg = 0; cseg < C_DIM / CSEG; ++cseg) {
      __syncthreads();  // previous consumers done before restage
      // stage x segment: 4096 floats as float4, coalesced rows of HW
#pragma unroll
      for (int i = 0; i < 4; ++i) {
        int fidx = t + 256 * i;
        int cs = fidx >> 4, p4 = (fidx & 15) << 2;
        *(float4*)&xs[cs * TPX + p4] =
            *(const float4*)&xb[(size_t)(cseg * CSEG + cs) * HW + p4];
      }
      if (et_flag) {
#pragma unroll
        for (int i = 0; i < 4; ++i) {
          int fidx = t + 256 * i;
          int cs = fidx >> 4, k4 = (fidx & 15) << 2;
          *(float4*)&es[cs * TKC + k4] =
              *(const float4*)&esrc[(size_t)(cseg * CSEG + cs) * K_CODES + k0 + k4];
        }
      } else {  // fallback if ws too small for ET: uncoalesced row reads
        for (int i = 0; i < 16; ++i) {
          int idx = t + 256 * i;
          int cs = idx >> 6, kk = idx & 63;
          es[cs * TKC + kk] = esrc[(size_t)(k0 + kk) * C_DIM + cseg * CSEG + cs];
        }
      }
      __syncthreads();

#pragma unroll 8
      for (int cs = 0; cs < CSEG; ++cs) {
        const float4 xv = *(const float4*)&xs[cs * TPX + (pg << 2)];
        const float4 ev = *(const float4*)&es[cs * TKC + (kg << 2)];
        acc00 += xv.x * ev.x; acc01 += xv.x * ev.y; acc02 += xv.x * ev.z; acc03 += xv.x * ev.w;
        acc10 += xv.y * ev.x; acc11 += xv.y * ev.y; acc12 += xv.y * ev.z; acc13 += xv.y * ev.w;
        acc20 += xv.z * ev.x; acc21 += xv.z * ev.y; acc22 += xv.z * ev.z; acc23 += xv.z * ev.w;
        acc30 += xv.w * ev.x; acc31 += xv.w * ev.y; acc32 += xv.w * ev.z; acc33 += xv.w * ev.w;
      }
    }

    // argmin update; ascending j => strict < keeps first minimal index
    {
      const int kb = k0 + (kg << 2);
      const float e20 = e2[kb], e21 = e2[kb + 1], e22 = e2[kb + 2], e23 = e2[kb + 3];
      float s;
      s = e20 - 2.f * acc00; if (s < best0) { best0 = s; bi0 = kb; }
      s = e21 - 2.f * acc01; if (s < best0) { best0 = s; bi0 = kb + 1; }
      s = e22 - 2.f * acc02; if (s < best0) { best0 = s; bi0 = kb + 2; }
      s = e23 - 2.f * acc03; if (s < best0) { best0 = s; bi0 = kb + 3; }
      s = e20 - 2.f * acc10; if (s < best1) { best1 = s; bi1 = kb; }
      s = e21 - 2.f * acc11; if (s < best1) { best1 = s; bi1 = kb + 1; }
      s = e22 - 2.f * acc12; if (s < best1) { best1 = s; bi1 = kb + 2; }
      s = e23 - 2.f * acc13; if (s < best1) { best1 = s; bi1 = kb + 3; }
      s = e20 - 2.f * acc20; if (s < best2) { best2 = s; bi2 = kb; }
      s = e21 - 2.f * acc21; if (s < best2) { best2 = s; bi2 = kb + 1; }
      s = e22 - 2.f * acc22; if (s < best2) { best2 = s; bi2 = kb + 2; }
      s = e23 - 2.f * acc23; if (s < best2) { best2 = s; bi2 = kb + 3; }
      s = e20 - 2.f * acc30; if (s < best3) { best3 = s; bi3 = kb; }
      s = e21 - 2.f * acc31; if (s < best3) { best3 = s; bi3 = kb + 1; }
      s = e22 - 2.f * acc32; if (s < best3) { best3 = s; bi3 = kb + 2; }
      s = e23 - 2.f * acc33; if (s < best3) { best3 = s; bi3 = kb + 3; }
    }
  }

  // cross-thread argmin reduce (16 kg candidates per pixel)
  __syncthreads();  // staging buffers dead; safe to alias as reduce arrays
  const int prow = pg << 2;
  red_d[(prow + 0) * 16 + kg] = best0; red_i[(prow + 0) * 16 + kg] = bi0;
  red_d[(prow + 1) * 16 + kg] = best1; red_i[(prow + 1) * 16 + kg] = bi1;
  red_d[(prow + 2) * 16 + kg] = best2; red_i[(prow + 2) * 16 + kg] = bi2;
  red_d[(prow + 3) * 16 + kg] = best3; red_i[(prow + 3) * 16 + kg] = bi3;
  __syncthreads();
  if (t < TPX) {
    float bd = red_d[t * 16];
    int   bk = red_i[t * 16];
    for (int g = 1; g < 16; ++g) {
      float d = red_d[t * 16 + g];
      int   k = red_i[t * 16 + g];
      if (d < bd || (d == bd && k < bk)) { bd = d; bk = k; }  // first-index ties
    }
    bidx_s[t] = bk;
  }
  __syncthreads();

  // gather + transposed coalesced store + loss partials
  float lsum = 0.f;
  float* outb = out + (size_t)b * C_DIM * HW + p0;
#pragma unroll 4
  for (int i = 0; i < 16; ++i) {
    int fidx = t + 256 * i;
    int c = fidx >> 4, p4 = (fidx & 15) << 2;
    const float4 x4 = *(const float4*)&xb[(size_t)c * HW + p4];
    const int j0 = bidx_s[p4], j1 = bidx_s[p4 + 1], j2 = bidx_s[p4 + 2], j3 = bidx_s[p4 + 3];
    const float q0 = emb[(size_t)j0 * C_DIM + c];
    const float q1 = emb[(size_t)j1 * C_DIM + c];
    const float q2 = emb[(size_t)j2 * C_DIM + c];
    const float q3 = emb[(size_t)j3 * C_DIM + c];
    const float d0 = q0 - x4.x, d1 = q1 - x4.y, d2 = q2 - x4.z, d3 = q3 - x4.w;
    lsum += d0 * d0 + d1 * d1 + d2 * d2 + d3 * d3;
    float4 o; o.x = q0; o.y = q1; o.z = q2; o.w = q3;
    *(float4*)&outb[(size_t)c * HW + p4] = o;
  }
  for (int off = 32; off > 0; off >>= 1) lsum += __shfl_down(lsum, off, 64);
  if ((t & 63) == 0) lred[t >> 6] = lsum;
  __syncthreads();
  if (t == 0) atomicAdd(loss_acc, lred[0] + lred[1] + lred[2] + lred[3]);
}

__global__ void k_final(const float* __restrict__ ws, float* __restrict__ out) {
  out[N_OUT] = 2.0f * ws[0] / (float)N_OUT;
}

extern "C" void kernel_launch(void* const* d_in, const int* in_sizes, int n_in,
                              void* d_out, int out_size, void* d_ws, size_t ws_size,
                              hipStream_t stream) {
  const float* x   = (const float*)d_in[0];
  const float* emb = (const float*)d_in[1];
  float* out = (float*)d_out;
  float* ws  = (float*)d_ws;
  float* e2  = ws + 64;
  float* et  = ws + 2048;
  const int use_et =
      (ws_size >= (size_t)(2048 + C_DIM * K_CODES) * sizeof(float)) ? 1 : 0;

  k_zero<<<1, 1, 0, stream>>>(ws);
  k_e2<<<K_CODES / 256, 256, 0, stream>>>(emb, e2);
  if (use_et) k_et<<<(C_DIM * K_CODES) / 256, 256, 0, stream>>>(emb, et);
  k_main<<<1024, 256, 0, stream>>>(x, emb, use_et ? et : emb, use_et, e2, out, ws);
  k_final<<<1, 1, 0, stream>>>(ws, out);
}